// Round 10
// baseline (52.134 us; speedup 1.0000x reference)
//
#include <hip/hip_runtime.h>

#define NROWS 8192
#define NCLS  100
#define NB    (NROWS / 4)        // 2048 blocks
#define LN2   0.6931471805599453f
#define LOG2E 1.4426950408889634f

#if __has_builtin(__builtin_amdgcn_exp2f)
#define EXP2F(x) __builtin_amdgcn_exp2f(x)
#else
#define EXP2F(x) __expf((x) * LN2)
#endif
#if __has_builtin(__builtin_amdgcn_logf)
#define LOG2F(x) __builtin_amdgcn_logf(x)
#else
#define LOG2F(x) (__logf(x) * LOG2E)
#endif

typedef _Float16 half8 __attribute__((ext_vector_type(8)));

// idx in [0,300) -> strict-upper-triangle 4x4 tile coords (I < J), J in [1,25)
#define TILEIJ(idx, I, J) \
    float s_##I = sqrtf(fmaf(8.f, (float)(idx), 1.f)); \
    int J = (int)((1.0f + s_##I) * 0.5f); \
    int I = (idx) - ((J * (J - 1)) >> 1);

// one pair term: P *= (Ea*Rb + Eb*Ra) = 2^-4*(2^(d/2)+2^(-d/2)); f(|d|)=2*log2(h)+8
#define HT(EA, RA, EB, RB, P) { P *= fmaf((EB), (RA), (EA) * (RB)); }

#define DECLQ(E, R) float E##0, E##1, E##2, E##3, R##0, R##1, R##2, R##3;
#define LOADQ(ptr, q, E, R) { half8 h_ = (ptr)[q]; \
    E##0 = (float)h_[0]; E##1 = (float)h_[1]; E##2 = (float)h_[2]; E##3 = (float)h_[3]; \
    R##0 = (float)h_[4]; R##1 = (float)h_[5]; R##2 = (float)h_[6]; R##3 = (float)h_[7]; }

#define TILE16S(P0, P1, P2, P3) \
  HT(Ea0, Ra0, Eb0, Rb0, P0) HT(Ea0, Ra0, Eb1, Rb1, P0) \
  HT(Ea0, Ra0, Eb2, Rb2, P0) HT(Ea0, Ra0, Eb3, Rb3, P0) \
  HT(Ea1, Ra1, Eb0, Rb0, P1) HT(Ea1, Ra1, Eb1, Rb1, P1) \
  HT(Ea1, Ra1, Eb2, Rb2, P1) HT(Ea1, Ra1, Eb3, Rb3, P1) \
  HT(Ea2, Ra2, Eb0, Rb0, P2) HT(Ea2, Ra2, Eb1, Rb1, P2) \
  HT(Ea2, Ra2, Eb2, Rb2, P2) HT(Ea2, Ra2, Eb3, Rb3, P2) \
  HT(Ea3, Ra3, Eb0, Rb0, P3) HT(Ea3, Ra3, Eb1, Rb1, P3) \
  HT(Ea3, Ra3, Eb2, Rb2, P3) HT(Ea3, Ra3, Eb3, Rb3, P3)

__global__ __launch_bounds__(256, 8) void cpc_fused(const float* __restrict__ in,
                                                    const int* __restrict__ tgt,
                                                    float* __restrict__ qb,
                                                    unsigned* __restrict__ cnt,
                                                    float* __restrict__ out) {
    __shared__ float sx[4][112];                       // x' (log2 domain), for xt lookup
    __shared__ __align__(16) _Float16 sq[4][28][8];    // quad records: E0..3 | R0..3 (f16)
    __shared__ float bred[4][3];
    __shared__ double sred[4][3];
    __shared__ unsigned lastflag;

    const int tid = threadIdx.x;
    const int w   = tid >> 6;                          // wave = row-in-block
    const int l   = tid & 63;
    const int row = blockIdx.x * 4 + w;
    const float* x = in + row * NCLS;
    _Float16* hq = (_Float16*)sq[w];

    // ---- stage: x' f32 (for xt/CE/BDC) + f16-packed (E,R) quads ----
    float x0 = x[l] * LOG2E;
    float E0f = EXP2F((x0 - 4.f) * 0.5f);
    float R0f = EXP2F((x0 + 4.f) * -0.5f);
    sx[w][l] = x0;
    hq[(l >> 2) * 8 + (l & 3)]     = (_Float16)E0f;
    hq[(l >> 2) * 8 + 4 + (l & 3)] = (_Float16)R0f;
    const bool v1 = (l < NCLS - 64);                   // lanes 0..35 hold a second class
    float x1 = 0.f, E1f = 0.f;
    if (v1) {
        int c = 64 + l;
        x1 = x[c] * LOG2E;
        E1f = EXP2F((x1 - 4.f) * 0.5f);
        float R1f = EXP2F((x1 + 4.f) * -0.5f);
        sx[w][c] = x1;
        hq[(c >> 2) * 8 + (c & 3)]     = (_Float16)E1f;
        hq[(c >> 2) * 8 + 4 + (c & 3)] = (_Float16)R1f;
    }
    __syncthreads();

    const int   t  = tgt[row];
    const float xt = sx[w][t];

    // ---- singles (full f32): sumexp via E^2, sum-x, target-pair stats ----
    float At, Pb, es, xs;
    {
        float a0 = fabsf(xt - x0);
        float e0 = (l == t) ? 0.f : EXP2F(-a0);
        At = a0; Pb = 1.f + e0;
        es = E0f * E0f;                                // = 2^(x0-4)
        xs = x0;
    }
    {
        float a1 = v1 ? fabsf(xt - x1) : 0.f;
        float e1 = (v1 && (64 + l) != t) ? EXP2F(-fabsf(xt - x1)) : 0.f;
        At += a1; Pb = fmaf(Pb, e1, Pb);
        es = v1 ? fmaf(E1f, E1f, es) : es;
        xs += x1;                                      // x1 = 0 when !v1
    }
    float lPb = LOG2F(Pb);

    const half8* pq = (const half8*)sq[w];

    // ---- off-diagonal 4x4 tiles: 300 tiles, 2 b128 reads each ----
    float P0 = 1.f, P1 = 1.f, P2 = 1.f, P3 = 1.f;
    float cst = 512.f;                                 // 4 iters x 16 terms x 8
#pragma unroll 1
    for (int it = 0; it < 4; ++it) {
        int idx = it * 64 + l;
        TILEIJ(idx, I, J)
        DECLQ(Ea, Ra) DECLQ(Eb, Rb)
        LOADQ(pq, I, Ea, Ra)
        LOADQ(pq, J, Eb, Rb)
        TILE16S(P0, P1, P2, P3)
    }
    {   // tail: idx = 256 + l, valid < 300
        int idx = 256 + l;
        bool tv = idx < 300;
        int idxc = tv ? idx : 0;
        TILEIJ(idxc, I, J)
        DECLQ(Ea, Ra) DECLQ(Eb, Rb)
        LOADQ(pq, I, Ea, Ra)
        LOADQ(pq, J, Eb, Rb)
        float S0 = P0, S1 = P1, S2 = P2, S3 = P3;
        TILE16S(P0, P1, P2, P3)
        P0 = tv ? P0 : S0; P1 = tv ? P1 : S1;
        P2 = tv ? P2 : S2; P3 = tv ? P3 : S3;
        cst += tv ? 128.f : 0.f;
    }
    // ---- diagonal tiles: lane<25 -> tile (l,l); all 16 entries, halved in account ----
    float Pd0 = 1.f, Pd1 = 1.f;
    {
        bool dv = l < 25;
        int I = dv ? l : 0;
        DECLQ(Ea, Ra)
        LOADQ(pq, I, Ea, Ra)
        float Eb0 = Ea0, Eb1 = Ea1, Eb2 = Ea2, Eb3 = Ea3;
        float Rb0 = Ra0, Rb1 = Ra1, Rb2 = Ra2, Rb3 = Ra3;
        TILE16S(Pd0, Pd1, Pd0, Pd1)
        Pd0 = dv ? Pd0 : 1.f;
        Pd1 = dv ? Pd1 : 1.f;
        cst += dv ? 64.f : 0.f;
    }

    // lS = sum of f over assigned pairs (+ halved selfs), log2 units
    float lS = 2.f * ((LOG2F(P0) + LOG2F(P1)) + (LOG2F(P2) + LOG2F(P3)))
             + LOG2F(Pd0 * Pd1) + cst;

    // ---- packed reduce: 3 values ----
    float r0 = es;                                     // -> sumexp * 2^-4
    float rU = xs + At + 2.f * lPb;                    // -> q1
    float rW = At + 2.f * lPb - lS;                    // -> q2
#pragma unroll
    for (int off = 32; off; off >>= 1) {
        r0 += __shfl_xor(r0, off, 64);
        rU += __shfl_xor(rU, off, 64);
        rW += __shfl_xor(rW, off, 64);
    }
    if (l == 0) {
        bred[w][0] = LN2 * (LOG2F(r0) + 4.f - xt);     // CE
        bred[w][1] = LN2 * (50.f * xt - 0.5f * rU);    // sum logsig(xt - rest)
        bred[w][2] = LN2 * (rW + 1.f);                 // rest-pairs (+99*logsig(0))
    }
    __syncthreads();
    if (tid < 3) {                                     // 3 block-partials, SoA [3][NB]
        float s = bred[0][tid] + bred[1][tid] + bred[2][tid] + bred[3][tid];
        qb[tid * NB + blockIdx.x] = s;
    }

    // ---- last-block-done finalize ----
    __syncthreads();
    if (tid == 0) {
        __threadfence();
        unsigned prev = atomicAdd(cnt, 1u);
        lastflag = (prev == (unsigned)(NB - 1)) ? 1u : 0u;
    }
    __syncthreads();
    if (lastflag) {
        __threadfence();
        const int lane = tid & 63, wid = tid >> 6;
        double a0 = 0, a1 = 0, a2 = 0;
#pragma unroll
        for (int it = 0; it < 2; ++it) {               // 2 x 256 x 4 = 2048 per comp
            int idx = (it * 256 + tid) * 4;
            float4 v0 = *(const float4*)(qb + idx);
            float4 v1 = *(const float4*)(qb + NB + idx);
            float4 v2 = *(const float4*)(qb + 2 * NB + idx);
            a0 += (double)v0.x; a0 += (double)v0.y; a0 += (double)v0.z; a0 += (double)v0.w;
            a1 += (double)v1.x; a1 += (double)v1.y; a1 += (double)v1.z; a1 += (double)v1.w;
            a2 += (double)v2.x; a2 += (double)v2.y; a2 += (double)v2.z; a2 += (double)v2.w;
        }
#pragma unroll
        for (int off = 32; off; off >>= 1) {
            a0 += __shfl_xor(a0, off, 64);
            a1 += __shfl_xor(a1, off, 64);
            a2 += __shfl_xor(a2, off, 64);
        }
        if (lane == 0) { sred[wid][0] = a0; sred[wid][1] = a1; sred[wid][2] = a2; }
        __syncthreads();
        if (tid == 0) {
            double ce  = (sred[0][0] + sred[1][0] + sred[2][0] + sred[3][0]) / (double)NROWS;
            double bdc = -(sred[0][1] + sred[1][1] + sred[2][1] + sred[3][1])
                         / (double)(NCLS - 1) / (double)NROWS;
            double bec = -0.5 * (sred[0][2] + sred[1][2] + sred[2][2] + sred[3][2])
                         / (double)(NCLS - 1) / (double)(NCLS - 2) / (double)NROWS;
            out[0] = (float)(ce + bdc + bec);
            out[1] = (float)ce;
            out[2] = (float)bdc;
            out[3] = (float)bec;
        }
    }
}

extern "C" void kernel_launch(void* const* d_in, const int* in_sizes, int n_in,
                              void* d_out, int out_size, void* d_ws, size_t ws_size,
                              hipStream_t stream) {
    const float* inputs  = (const float*)d_in[0];
    const int*   targets = (const int*)d_in[1];
    float*       out     = (float*)d_out;
    float*       qb      = (float*)d_ws;               // [3][2048] f32 = 24 KB
    unsigned*    cnt     = (unsigned*)((char*)d_ws + 32768);

    hipMemsetAsync(cnt, 0, sizeof(unsigned), stream);
    cpc_fused<<<NB, 256, 0, stream>>>(inputs, targets, qb, cnt, out);
}

// Round 11
// 38.725 us; speedup vs baseline: 1.3463x; 1.3463x over previous
//
#include <hip/hip_runtime.h>

#define NROWS 8192
#define NCLS  100
#define NB    (NROWS / 4)        // 2048 blocks
#define LN2   0.6931471805599453f
#define LOG2E 1.4426950408889634f

#if __has_builtin(__builtin_amdgcn_exp2f)
#define EXP2F(x) __builtin_amdgcn_exp2f(x)
#else
#define EXP2F(x) __expf((x) * LN2)
#endif
#if __has_builtin(__builtin_amdgcn_logf)
#define LOG2F(x) __builtin_amdgcn_logf(x)
#else
#define LOG2F(x) (__logf(x) * LOG2E)
#endif

typedef _Float16 half8 __attribute__((ext_vector_type(8)));

// idx in [0,300) -> strict-upper-triangle 4x4 tile coords (I < J), J in [1,25)
#define TILEIJ(idx, I, J) \
    float s_##I = sqrtf(fmaf(8.f, (float)(idx), 1.f)); \
    int J = (int)((1.0f + s_##I) * 0.5f); \
    int I = (idx) - ((J * (J - 1)) >> 1);

// one pair term: P *= (Ea*Rb + Eb*Ra) = 2^-4*(2^(d/2)+2^(-d/2)); f(|d|)=2*log2(h)+8
#define HT(EA, RA, EB, RB, P) { P *= fmaf((EB), (RA), (EA) * (RB)); }

#define DECLQ(E, R) float E##0, E##1, E##2, E##3, R##0, R##1, R##2, R##3;
#define LOADQ(ptr, q, E, R) { half8 h_ = (ptr)[q]; \
    E##0 = (float)h_[0]; E##1 = (float)h_[1]; E##2 = (float)h_[2]; E##3 = (float)h_[3]; \
    R##0 = (float)h_[4]; R##1 = (float)h_[5]; R##2 = (float)h_[6]; R##3 = (float)h_[7]; }

#define TILE16S(P0, P1, P2, P3) \
  HT(Ea0, Ra0, Eb0, Rb0, P0) HT(Ea0, Ra0, Eb1, Rb1, P0) \
  HT(Ea0, Ra0, Eb2, Rb2, P0) HT(Ea0, Ra0, Eb3, Rb3, P0) \
  HT(Ea1, Ra1, Eb0, Rb0, P1) HT(Ea1, Ra1, Eb1, Rb1, P1) \
  HT(Ea1, Ra1, Eb2, Rb2, P1) HT(Ea1, Ra1, Eb3, Rb3, P1) \
  HT(Ea2, Ra2, Eb0, Rb0, P2) HT(Ea2, Ra2, Eb1, Rb1, P2) \
  HT(Ea2, Ra2, Eb2, Rb2, P2) HT(Ea2, Ra2, Eb3, Rb3, P2) \
  HT(Ea3, Ra3, Eb0, Rb0, P3) HT(Ea3, Ra3, Eb1, Rb1, P3) \
  HT(Ea3, Ra3, Eb2, Rb2, P3) HT(Ea3, Ra3, Eb3, Rb3, P3)

__global__ __launch_bounds__(256, 8) void cpc_fused(const float* __restrict__ in,
                                                    const int* __restrict__ tgt,
                                                    float* __restrict__ qb,
                                                    unsigned* __restrict__ cnt,
                                                    float* __restrict__ out) {
    __shared__ float sx[4][112];                       // x' (log2 domain), for xt lookup
    __shared__ __align__(16) _Float16 sq[4][28][8];    // quad records: E0..3 | R0..3 (f16)
    __shared__ float bred[4][3];
    __shared__ double sred[4][3];
    __shared__ unsigned lastflag;

    const int tid = threadIdx.x;
    const int w   = tid >> 6;                          // wave = row-in-block
    const int l   = tid & 63;
    const int row = blockIdx.x * 4 + w;
    const float* x = in + row * NCLS;
    _Float16* hq = (_Float16*)sq[w];

    // ---- stage: x' f32 (for xt/CE/BDC) + f16-packed (E,R) quads ----
    float x0 = x[l] * LOG2E;
    float E0f = EXP2F((x0 - 4.f) * 0.5f);
    float R0f = EXP2F((x0 + 4.f) * -0.5f);
    sx[w][l] = x0;
    hq[(l >> 2) * 8 + (l & 3)]     = (_Float16)E0f;
    hq[(l >> 2) * 8 + 4 + (l & 3)] = (_Float16)R0f;
    const bool v1 = (l < NCLS - 64);                   // lanes 0..35 hold a second class
    float x1 = 0.f, E1f = 0.f;
    if (v1) {
        int c = 64 + l;
        x1 = x[c] * LOG2E;
        E1f = EXP2F((x1 - 4.f) * 0.5f);
        float R1f = EXP2F((x1 + 4.f) * -0.5f);
        sx[w][c] = x1;
        hq[(c >> 2) * 8 + (c & 3)]     = (_Float16)E1f;
        hq[(c >> 2) * 8 + 4 + (c & 3)] = (_Float16)R1f;
    }
    __syncthreads();

    const int   t  = tgt[row];
    const float xt = sx[w][t];

    // ---- singles (full f32): sumexp via E^2, sum-x, target-pair stats ----
    float At, Pb, es, xs;
    {
        float a0 = fabsf(xt - x0);
        float e0 = (l == t) ? 0.f : EXP2F(-a0);
        At = a0; Pb = 1.f + e0;
        es = E0f * E0f;                                // = 2^(x0-4)
        xs = x0;
    }
    {
        float a1 = v1 ? fabsf(xt - x1) : 0.f;
        float e1 = (v1 && (64 + l) != t) ? EXP2F(-fabsf(xt - x1)) : 0.f;
        At += a1; Pb = fmaf(Pb, e1, Pb);
        es = v1 ? fmaf(E1f, E1f, es) : es;
        xs += x1;                                      // x1 = 0 when !v1
    }
    float lPb = LOG2F(Pb);

    const half8* pq = (const half8*)sq[w];

    // ---- off-diagonal 4x4 tiles: 300 tiles, 2 b128 reads each ----
    float P0 = 1.f, P1 = 1.f, P2 = 1.f, P3 = 1.f;
    float cst = 512.f;                                 // 4 iters x 16 terms x 8
#pragma unroll 1
    for (int it = 0; it < 4; ++it) {
        int idx = it * 64 + l;
        TILEIJ(idx, I, J)
        DECLQ(Ea, Ra) DECLQ(Eb, Rb)
        LOADQ(pq, I, Ea, Ra)
        LOADQ(pq, J, Eb, Rb)
        TILE16S(P0, P1, P2, P3)
    }
    {   // tail: idx = 256 + l, valid < 300
        int idx = 256 + l;
        bool tv = idx < 300;
        int idxc = tv ? idx : 0;
        TILEIJ(idxc, I, J)
        DECLQ(Ea, Ra) DECLQ(Eb, Rb)
        LOADQ(pq, I, Ea, Ra)
        LOADQ(pq, J, Eb, Rb)
        float S0 = P0, S1 = P1, S2 = P2, S3 = P3;
        TILE16S(P0, P1, P2, P3)
        P0 = tv ? P0 : S0; P1 = tv ? P1 : S1;
        P2 = tv ? P2 : S2; P3 = tv ? P3 : S3;
        cst += tv ? 128.f : 0.f;
    }
    // ---- diagonal tiles: lane<25 -> tile (l,l); all 16 entries, halved in account ----
    float Pd0 = 1.f, Pd1 = 1.f;
    {
        bool dv = l < 25;
        int I = dv ? l : 0;
        DECLQ(Ea, Ra)
        LOADQ(pq, I, Ea, Ra)
        float Eb0 = Ea0, Eb1 = Ea1, Eb2 = Ea2, Eb3 = Ea3;
        float Rb0 = Ra0, Rb1 = Ra1, Rb2 = Ra2, Rb3 = Ra3;
        TILE16S(Pd0, Pd1, Pd0, Pd1)
        Pd0 = dv ? Pd0 : 1.f;
        Pd1 = dv ? Pd1 : 1.f;
        cst += dv ? 64.f : 0.f;
    }

    // lS = sum of f over assigned pairs (+ halved selfs), log2 units
    float lS = 2.f * ((LOG2F(P0) + LOG2F(P1)) + (LOG2F(P2) + LOG2F(P3)))
             + LOG2F(Pd0 * Pd1) + cst;

    // ---- packed reduce: 3 values ----
    float r0 = es;                                     // -> sumexp * 2^-4
    float rU = xs + At + 2.f * lPb;                    // -> q1
    float rW = At + 2.f * lPb - lS;                    // -> q2
#pragma unroll
    for (int off = 32; off; off >>= 1) {
        r0 += __shfl_xor(r0, off, 64);
        rU += __shfl_xor(rU, off, 64);
        rW += __shfl_xor(rW, off, 64);
    }
    if (l == 0) {
        bred[w][0] = LN2 * (LOG2F(r0) + 4.f - xt);     // CE
        bred[w][1] = LN2 * (50.f * xt - 0.5f * rU);    // sum logsig(xt - rest)
        bred[w][2] = LN2 * (rW + 1.f);                 // rest-pairs (+99*logsig(0))
    }
    __syncthreads();

    // ---- publish partials at the coherent point (no fence): atomicExch per slot ----
    if (tid < 3) {
        float s = bred[0][tid] + bred[1][tid] + bred[2][tid] + bred[3][tid];
        atomicExch(qb + tid * NB + blockIdx.x, s);     // single writer per slot
    }
    // wave 0: wait for our value-atomics to commit before signaling the counter
    asm volatile("s_waitcnt vmcnt(0)" ::: "memory");
    if (tid == 0) {
        unsigned prev = atomicAdd(cnt, 1u);
        lastflag = (prev == (unsigned)(NB - 1)) ? 1u : 0u;
    }
    __syncthreads();

    // ---- ONE block pays ONE fence, then reduces the 24 KB of partials ----
    if (lastflag) {
        __threadfence();                               // acquire: invalidate stale lines
        const int lane = tid & 63, wid = tid >> 6;
        double a0 = 0, a1 = 0, a2 = 0;
#pragma unroll
        for (int it = 0; it < 2; ++it) {               // 2 x 256 x 4 = 2048 per comp
            int idx = (it * 256 + tid) * 4;
            float4 v0 = *(const float4*)(qb + idx);
            float4 v1 = *(const float4*)(qb + NB + idx);
            float4 v2 = *(const float4*)(qb + 2 * NB + idx);
            a0 += (double)v0.x; a0 += (double)v0.y; a0 += (double)v0.z; a0 += (double)v0.w;
            a1 += (double)v1.x; a1 += (double)v1.y; a1 += (double)v1.z; a1 += (double)v1.w;
            a2 += (double)v2.x; a2 += (double)v2.y; a2 += (double)v2.z; a2 += (double)v2.w;
        }
#pragma unroll
        for (int off = 32; off; off >>= 1) {
            a0 += __shfl_xor(a0, off, 64);
            a1 += __shfl_xor(a1, off, 64);
            a2 += __shfl_xor(a2, off, 64);
        }
        if (lane == 0) { sred[wid][0] = a0; sred[wid][1] = a1; sred[wid][2] = a2; }
        __syncthreads();
        if (tid == 0) {
            double ce  = (sred[0][0] + sred[1][0] + sred[2][0] + sred[3][0]) / (double)NROWS;
            double bdc = -(sred[0][1] + sred[1][1] + sred[2][1] + sred[3][1])
                         / (double)(NCLS - 1) / (double)NROWS;
            double bec = -0.5 * (sred[0][2] + sred[1][2] + sred[2][2] + sred[3][2])
                         / (double)(NCLS - 1) / (double)(NCLS - 2) / (double)NROWS;
            out[0] = (float)(ce + bdc + bec);
            out[1] = (float)ce;
            out[2] = (float)bdc;
            out[3] = (float)bec;
        }
    }
}

extern "C" void kernel_launch(void* const* d_in, const int* in_sizes, int n_in,
                              void* d_out, int out_size, void* d_ws, size_t ws_size,
                              hipStream_t stream) {
    const float* inputs  = (const float*)d_in[0];
    const int*   targets = (const int*)d_in[1];
    float*       out     = (float*)d_out;
    float*       qb      = (float*)d_ws;               // [3][2048] f32 = 24 KB (atomicExch-written)
    unsigned*    cnt     = (unsigned*)((char*)d_ws + 32768);

    hipMemsetAsync(cnt, 0, sizeof(unsigned), stream);
    cpc_fused<<<NB, 256, 0, stream>>>(inputs, targets, qb, cnt, out);
}

// Round 12
// 16.095 us; speedup vs baseline: 3.2391x; 2.4060x over previous
//
#include <hip/hip_runtime.h>

#define NROWS 8192
#define NCLS  100
#define NB    (NROWS / 4)        // 2048 blocks
#define LN2   0.6931471805599453f
#define LOG2E 1.4426950408889634f

#if __has_builtin(__builtin_amdgcn_exp2f)
#define EXP2F(x) __builtin_amdgcn_exp2f(x)
#else
#define EXP2F(x) __expf((x) * LN2)
#endif
#if __has_builtin(__builtin_amdgcn_logf)
#define LOG2F(x) __builtin_amdgcn_logf(x)
#else
#define LOG2F(x) (__logf(x) * LOG2E)
#endif

typedef _Float16 half8 __attribute__((ext_vector_type(8)));

// idx in [0,300) -> strict-upper-triangle 4x4 tile coords (I < J), J in [1,25)
#define TILEIJ(idx, I, J) \
    float s_##I = sqrtf(fmaf(8.f, (float)(idx), 1.f)); \
    int J = (int)((1.0f + s_##I) * 0.5f); \
    int I = (idx) - ((J * (J - 1)) >> 1);

// one pair term: P *= (Ea*Rb + Eb*Ra) = 2^-4*(2^(d/2)+2^(-d/2)); f(|d|)=2*log2(h)+8
#define HT(EA, RA, EB, RB, P) { P *= fmaf((EB), (RA), (EA) * (RB)); }

#define DECLQ(E, R) float E##0, E##1, E##2, E##3, R##0, R##1, R##2, R##3;
#define LOADQ(ptr, q, E, R) { half8 h_ = (ptr)[q]; \
    E##0 = (float)h_[0]; E##1 = (float)h_[1]; E##2 = (float)h_[2]; E##3 = (float)h_[3]; \
    R##0 = (float)h_[4]; R##1 = (float)h_[5]; R##2 = (float)h_[6]; R##3 = (float)h_[7]; }

#define TILE16S(P0, P1, P2, P3) \
  HT(Ea0, Ra0, Eb0, Rb0, P0) HT(Ea0, Ra0, Eb1, Rb1, P0) \
  HT(Ea0, Ra0, Eb2, Rb2, P0) HT(Ea0, Ra0, Eb3, Rb3, P0) \
  HT(Ea1, Ra1, Eb0, Rb0, P1) HT(Ea1, Ra1, Eb1, Rb1, P1) \
  HT(Ea1, Ra1, Eb2, Rb2, P1) HT(Ea1, Ra1, Eb3, Rb3, P1) \
  HT(Ea2, Ra2, Eb0, Rb0, P2) HT(Ea2, Ra2, Eb1, Rb1, P2) \
  HT(Ea2, Ra2, Eb2, Rb2, P2) HT(Ea2, Ra2, Eb3, Rb3, P2) \
  HT(Ea3, Ra3, Eb0, Rb0, P3) HT(Ea3, Ra3, Eb1, Rb1, P3) \
  HT(Ea3, Ra3, Eb2, Rb2, P3) HT(Ea3, Ra3, Eb3, Rb3, P3)

__global__ __launch_bounds__(256, 8) void cpc_rows(const float* __restrict__ in,
                                                   const int* __restrict__ tgt,
                                                   float* __restrict__ qb) {
    __shared__ float sx[4][112];                       // x' (log2 domain), for xt lookup
    __shared__ __align__(16) _Float16 sq[4][28][8];    // quad records: E0..3 | R0..3 (f16)
    __shared__ float bred[4][3];

    const int tid = threadIdx.x;
    const int w   = tid >> 6;                          // wave = row-in-block
    const int l   = tid & 63;
    const int row = blockIdx.x * 4 + w;
    const float* x = in + row * NCLS;
    _Float16* hq = (_Float16*)sq[w];

    // ---- stage: x' f32 (for xt/CE/BDC) + f16-packed (E,R) quads ----
    float x0 = x[l] * LOG2E;
    float E0f = EXP2F((x0 - 4.f) * 0.5f);
    float R0f = EXP2F((x0 + 4.f) * -0.5f);
    sx[w][l] = x0;
    hq[(l >> 2) * 8 + (l & 3)]     = (_Float16)E0f;
    hq[(l >> 2) * 8 + 4 + (l & 3)] = (_Float16)R0f;
    const bool v1 = (l < NCLS - 64);                   // lanes 0..35 hold a second class
    float x1 = 0.f, E1f = 0.f;
    if (v1) {
        int c = 64 + l;
        x1 = x[c] * LOG2E;
        E1f = EXP2F((x1 - 4.f) * 0.5f);
        float R1f = EXP2F((x1 + 4.f) * -0.5f);
        sx[w][c] = x1;
        hq[(c >> 2) * 8 + (c & 3)]     = (_Float16)E1f;
        hq[(c >> 2) * 8 + 4 + (c & 3)] = (_Float16)R1f;
    }
    __syncthreads();

    const int   t  = tgt[row];
    const float xt = sx[w][t];

    // ---- singles (full f32): sumexp via E^2, sum-x, target-pair stats ----
    float At, Pb, es, xs;
    {
        float a0 = fabsf(xt - x0);
        float e0 = (l == t) ? 0.f : EXP2F(-a0);
        At = a0; Pb = 1.f + e0;
        es = E0f * E0f;                                // = 2^(x0-4)
        xs = x0;
    }
    {
        float a1 = v1 ? fabsf(xt - x1) : 0.f;
        float e1 = (v1 && (64 + l) != t) ? EXP2F(-fabsf(xt - x1)) : 0.f;
        At += a1; Pb = fmaf(Pb, e1, Pb);
        es = v1 ? fmaf(E1f, E1f, es) : es;
        xs += x1;                                      // x1 = 0 when !v1
    }
    float lPb = LOG2F(Pb);

    const half8* pq = (const half8*)sq[w];

    // ---- off-diagonal 4x4 tiles: 300 tiles, 2 b128 reads each ----
    float P0 = 1.f, P1 = 1.f, P2 = 1.f, P3 = 1.f;
    float cst = 512.f;                                 // 4 iters x 16 terms x 8
#pragma unroll 1
    for (int it = 0; it < 4; ++it) {
        int idx = it * 64 + l;
        TILEIJ(idx, I, J)
        DECLQ(Ea, Ra) DECLQ(Eb, Rb)
        LOADQ(pq, I, Ea, Ra)
        LOADQ(pq, J, Eb, Rb)
        TILE16S(P0, P1, P2, P3)
    }
    {   // tail: idx = 256 + l, valid < 300
        int idx = 256 + l;
        bool tv = idx < 300;
        int idxc = tv ? idx : 0;
        TILEIJ(idxc, I, J)
        DECLQ(Ea, Ra) DECLQ(Eb, Rb)
        LOADQ(pq, I, Ea, Ra)
        LOADQ(pq, J, Eb, Rb)
        float S0 = P0, S1 = P1, S2 = P2, S3 = P3;
        TILE16S(P0, P1, P2, P3)
        P0 = tv ? P0 : S0; P1 = tv ? P1 : S1;
        P2 = tv ? P2 : S2; P3 = tv ? P3 : S3;
        cst += tv ? 128.f : 0.f;
    }
    // ---- diagonal tiles: lane<25 -> tile (l,l); all 16 entries, halved in account ----
    float Pd0 = 1.f, Pd1 = 1.f;
    {
        bool dv = l < 25;
        int I = dv ? l : 0;
        DECLQ(Ea, Ra)
        LOADQ(pq, I, Ea, Ra)
        float Eb0 = Ea0, Eb1 = Ea1, Eb2 = Ea2, Eb3 = Ea3;
        float Rb0 = Ra0, Rb1 = Ra1, Rb2 = Ra2, Rb3 = Ra3;
        TILE16S(Pd0, Pd1, Pd0, Pd1)
        Pd0 = dv ? Pd0 : 1.f;
        Pd1 = dv ? Pd1 : 1.f;
        cst += dv ? 64.f : 0.f;
    }

    // lS = sum of f over assigned pairs (+ halved selfs), log2 units
    float lS = 2.f * ((LOG2F(P0) + LOG2F(P1)) + (LOG2F(P2) + LOG2F(P3)))
             + LOG2F(Pd0 * Pd1) + cst;

    // ---- packed reduce: 3 values ----
    float r0 = es;                                     // -> sumexp * 2^-4
    float rU = xs + At + 2.f * lPb;                    // -> q1
    float rW = At + 2.f * lPb - lS;                    // -> q2
#pragma unroll
    for (int off = 32; off; off >>= 1) {
        r0 += __shfl_xor(r0, off, 64);
        rU += __shfl_xor(rU, off, 64);
        rW += __shfl_xor(rW, off, 64);
    }
    if (l == 0) {
        bred[w][0] = LN2 * (LOG2F(r0) + 4.f - xt);     // CE
        bred[w][1] = LN2 * (50.f * xt - 0.5f * rU);    // sum logsig(xt - rest)
        bred[w][2] = LN2 * (rW + 1.f);                 // rest-pairs (+99*logsig(0))
    }
    __syncthreads();
    if (tid < 3) {                                     // 3 block-partials, SoA [3][NB]
        float s = bred[0][tid] + bred[1][tid] + bred[2][tid] + bred[3][tid];
        qb[tid * NB + blockIdx.x] = s;
    }
}

__global__ __launch_bounds__(256) void cpc_final(const float* __restrict__ qb,
                                                 float* __restrict__ out) {
    __shared__ double sred[4][3];
    const int tid = threadIdx.x;
    const int lane = tid & 63, wid = tid >> 6;
    double a0 = 0, a1 = 0, a2 = 0;
#pragma unroll
    for (int it = 0; it < 2; ++it) {                   // 2 x 256 x 4 = 2048 per comp
        int idx = (it * 256 + tid) * 4;
        float4 v0 = *(const float4*)(qb + idx);
        float4 v1 = *(const float4*)(qb + NB + idx);
        float4 v2 = *(const float4*)(qb + 2 * NB + idx);
        a0 += (double)v0.x; a0 += (double)v0.y; a0 += (double)v0.z; a0 += (double)v0.w;
        a1 += (double)v1.x; a1 += (double)v1.y; a1 += (double)v1.z; a1 += (double)v1.w;
        a2 += (double)v2.x; a2 += (double)v2.y; a2 += (double)v2.z; a2 += (double)v2.w;
    }
#pragma unroll
    for (int off = 32; off; off >>= 1) {
        a0 += __shfl_xor(a0, off, 64);
        a1 += __shfl_xor(a1, off, 64);
        a2 += __shfl_xor(a2, off, 64);
    }
    if (lane == 0) { sred[wid][0] = a0; sred[wid][1] = a1; sred[wid][2] = a2; }
    __syncthreads();
    if (tid == 0) {
        double ce  = (sred[0][0] + sred[1][0] + sred[2][0] + sred[3][0]) / (double)NROWS;
        double bdc = -(sred[0][1] + sred[1][1] + sred[2][1] + sred[3][1])
                     / (double)(NCLS - 1) / (double)NROWS;
        double bec = -0.5 * (sred[0][2] + sred[1][2] + sred[2][2] + sred[3][2])
                     / (double)(NCLS - 1) / (double)(NCLS - 2) / (double)NROWS;
        out[0] = (float)(ce + bdc + bec);
        out[1] = (float)ce;
        out[2] = (float)bdc;
        out[3] = (float)bec;
    }
}

extern "C" void kernel_launch(void* const* d_in, const int* in_sizes, int n_in,
                              void* d_out, int out_size, void* d_ws, size_t ws_size,
                              hipStream_t stream) {
    const float* inputs  = (const float*)d_in[0];
    const int*   targets = (const int*)d_in[1];
    float*       out     = (float*)d_out;
    float*       qb      = (float*)d_ws;               // [3][2048] f32 = 24 KB

    cpc_rows<<<NB, 256, 0, stream>>>(inputs, targets, qb);
    cpc_final<<<1, 256, 0, stream>>>(qb, out);
}